// Round 2
// baseline (2539.791 us; speedup 1.0000x reference)
//
#include <hip/hip_runtime.h>
#include <hip/hip_bf16.h>

// Problem constants (fixed by reference setup_inputs)
#define N_ATOMS   100000
#define N_BONDS   200000
#define MAX_NB    6
#define HIDDEN    300
#define ATOM_FDIM 133
#define BOND_FDIM 147
#define N_MOLS    5000
#define APM       20      // atoms per mol

#define MB_ROWS (N_BONDS + 1)   // 200001
#define MA_ROWS (N_ATOMS + 1)   // 100001

#define BM 64
#define BN 64
#define BK 16

typedef unsigned short bf16_t;

__device__ __forceinline__ float bf2f(unsigned short u) {
    union { unsigned int i; float f; } x; x.i = ((unsigned int)u) << 16; return x.f;
}
__device__ __forceinline__ unsigned short f2bf(float f) {
    union { float f; unsigned int i; } x; x.f = f;
    unsigned int r = x.i + 0x7FFFu + ((x.i >> 16) & 1u);   // RNE (finite values)
    return (unsigned short)(r >> 16);
}

// ---------------------------------------------------------------------------
// GEMM1: Y(bf16) = relu( X(fp32 [M,147]) @ W(fp32 [147,300]) )
// Scalar A staging (147-col rows are NOT 16B aligned -> no vector loads on X).
// ---------------------------------------------------------------------------
__global__ __launch_bounds__(256) void gemm_in(
    const float* __restrict__ X, const float* __restrict__ W,
    bf16_t* __restrict__ Y, int M)
{
    const int K = BOND_FDIM, N = HIDDEN;
    __shared__ float As[BK][BM];
    __shared__ float Bs[BK][BN];
    const int bm = blockIdx.y * BM, bn = blockIdx.x * BN;
    const int tid = threadIdx.x, tx = tid & 15, ty = tid >> 4;
    float acc[4][4] = {};

    for (int k0 = 0; k0 < K; k0 += BK) {
        {   // A tile: 4 scalar loads per thread
            int r = tid >> 2, kk = (tid & 3) * 4, row = bm + r;
            #pragma unroll
            for (int t = 0; t < 4; ++t) {
                int k = k0 + kk + t;
                As[kk + t][r] = (row < M && k < K) ? X[(size_t)row * K + k] : 0.f;
            }
        }
        {   // B tile: aligned float4 (W rows are 300 floats = 1200 B)
            int kr_ = tid >> 4, cc = (tid & 15) * 4;
            int krow = k0 + kr_, col = bn + cc;
            float4 v = make_float4(0.f, 0.f, 0.f, 0.f);
            if (krow < K && col < N) v = *(const float4*)(W + (size_t)krow * N + col);
            *(float4*)&Bs[kr_][cc] = v;
        }
        __syncthreads();
        #pragma unroll
        for (int k = 0; k < BK; ++k) {
            float4 a4 = *(float4*)&As[k][ty * 4];
            float4 b4 = *(float4*)&Bs[k][tx * 4];
            float a[4] = {a4.x, a4.y, a4.z, a4.w};
            float b[4] = {b4.x, b4.y, b4.z, b4.w};
            #pragma unroll
            for (int i = 0; i < 4; ++i)
                #pragma unroll
                for (int j = 0; j < 4; ++j)
                    acc[i][j] += a[i] * b[j];
        }
        __syncthreads();
    }
    #pragma unroll
    for (int i = 0; i < 4; ++i) {
        int row = bm + ty * 4 + i;
        if (row >= M) continue;
        #pragma unroll
        for (int j = 0; j < 4; ++j) {
            int col = bn + tx * 4 + j;
            if (col >= N) continue;
            float v = acc[i][j];
            Y[(size_t)row * N + col] = f2bf(v > 0.f ? v : 0.f);
        }
    }
}

// ---------------------------------------------------------------------------
// Message-passing GEMM with FUSED bond gather:
//   X[row][k] = amsg[b2a[row]][k] - cur[b2revb[row]][k]   (virtual, bf16)
//   Y(bf16) = relu( addend(bf16) + X @ W(fp32 [300,300]) )
// Y may alias addend (element read-before-write in same thread) but must NOT
// alias cur.
// ---------------------------------------------------------------------------
__global__ __launch_bounds__(256) void gemm_mp(
    const bf16_t* __restrict__ amsg, const bf16_t* __restrict__ cur,
    const int* __restrict__ b2a, const int* __restrict__ b2revb,
    const float* __restrict__ W, const bf16_t* __restrict__ addend,
    bf16_t* __restrict__ Y, int M)
{
    const int K = HIDDEN, N = HIDDEN;
    __shared__ float As[BK][BM];
    __shared__ float Bs[BK][BN];
    const int bm = blockIdx.y * BM, bn = blockIdx.x * BN;
    const int tid = threadIdx.x, tx = tid & 15, ty = tid >> 4;
    float acc[4][4] = {};

    for (int k0 = 0; k0 < K; k0 += BK) {
        {   // A tile: gather two ushort4 (8B, aligned: row stride 600 B, k%4==0)
            int r = tid >> 2, kk = (tid & 3) * 4, row = bm + r;
            float4 av = make_float4(0.f, 0.f, 0.f, 0.f);
            int k = k0 + kk;
            if (row < M && k < K) {   // K%4==0 -> k<K implies full 4 valid
                int a  = b2a[row];
                int rb = b2revb[row];
                ushort4 u1 = *(const ushort4*)(amsg + (size_t)a  * K + k);
                ushort4 u2 = *(const ushort4*)(cur  + (size_t)rb * K + k);
                av.x = bf2f(u1.x) - bf2f(u2.x);
                av.y = bf2f(u1.y) - bf2f(u2.y);
                av.z = bf2f(u1.z) - bf2f(u2.z);
                av.w = bf2f(u1.w) - bf2f(u2.w);
            }
            As[kk + 0][r] = av.x;
            As[kk + 1][r] = av.y;
            As[kk + 2][r] = av.z;
            As[kk + 3][r] = av.w;
        }
        {   // B tile
            int kr_ = tid >> 4, cc = (tid & 15) * 4;
            int krow = k0 + kr_, col = bn + cc;
            float4 v = make_float4(0.f, 0.f, 0.f, 0.f);
            if (krow < K && col < N) v = *(const float4*)(W + (size_t)krow * N + col);
            *(float4*)&Bs[kr_][cc] = v;
        }
        __syncthreads();
        #pragma unroll
        for (int k = 0; k < BK; ++k) {
            float4 a4 = *(float4*)&As[k][ty * 4];
            float4 b4 = *(float4*)&Bs[k][tx * 4];
            float a[4] = {a4.x, a4.y, a4.z, a4.w};
            float b[4] = {b4.x, b4.y, b4.z, b4.w};
            #pragma unroll
            for (int i = 0; i < 4; ++i)
                #pragma unroll
                for (int j = 0; j < 4; ++j)
                    acc[i][j] += a[i] * b[j];
        }
        __syncthreads();
    }
    #pragma unroll
    for (int i = 0; i < 4; ++i) {
        int row = bm + ty * 4 + i;
        if (row >= M) continue;
        #pragma unroll
        for (int j = 0; j < 4; ++j) {
            int col = bn + tx * 4 + j;
            if (col >= N) continue;
            float v = acc[i][j] + bf2f(addend[(size_t)row * N + col]);
            Y[(size_t)row * N + col] = f2bf(v > 0.f ? v : 0.f);
        }
    }
}

// ---------------------------------------------------------------------------
// Readout GEMM, virtual concat A = [f_atoms fp32 (133) | amsg bf16 (300)]:
//   Y(bf16) = relu( A @ W_o(fp32 [433,300]) + b_o )
// ---------------------------------------------------------------------------
__global__ __launch_bounds__(256) void gemm_out(
    const float* __restrict__ f_atoms, const bf16_t* __restrict__ amsg,
    const float* __restrict__ W, const float* __restrict__ bias,
    bf16_t* __restrict__ Y, int M)
{
    const int K = ATOM_FDIM + HIDDEN;   // 433
    const int N = HIDDEN;
    __shared__ float As[BK][BM];
    __shared__ float Bs[BK][BN];
    const int bm = blockIdx.y * BM, bn = blockIdx.x * BN;
    const int tid = threadIdx.x, tx = tid & 15, ty = tid >> 4;
    float acc[4][4] = {};

    for (int k0 = 0; k0 < K; k0 += BK) {
        {   // A tile: scalar loads (concat boundary + 133-col alignment)
            int r = tid >> 2, kk = (tid & 3) * 4, row = bm + r;
            #pragma unroll
            for (int t = 0; t < 4; ++t) {
                int k = k0 + kk + t;
                float v = 0.f;
                if (row < M && k < K) {
                    v = (k < ATOM_FDIM)
                        ? f_atoms[(size_t)row * ATOM_FDIM + k]
                        : bf2f(amsg[(size_t)row * HIDDEN + (k - ATOM_FDIM)]);
                }
                As[kk + t][r] = v;
            }
        }
        {   // B tile
            int kr_ = tid >> 4, cc = (tid & 15) * 4;
            int krow = k0 + kr_, col = bn + cc;
            float4 v = make_float4(0.f, 0.f, 0.f, 0.f);
            if (krow < K && col < N) v = *(const float4*)(W + (size_t)krow * N + col);
            *(float4*)&Bs[kr_][cc] = v;
        }
        __syncthreads();
        #pragma unroll
        for (int k = 0; k < BK; ++k) {
            float4 a4 = *(float4*)&As[k][ty * 4];
            float4 b4 = *(float4*)&Bs[k][tx * 4];
            float a[4] = {a4.x, a4.y, a4.z, a4.w};
            float b[4] = {b4.x, b4.y, b4.z, b4.w};
            #pragma unroll
            for (int i = 0; i < 4; ++i)
                #pragma unroll
                for (int j = 0; j < 4; ++j)
                    acc[i][j] += a[i] * b[j];
        }
        __syncthreads();
    }
    #pragma unroll
    for (int i = 0; i < 4; ++i) {
        int row = bm + ty * 4 + i;
        if (row >= M) continue;
        #pragma unroll
        for (int j = 0; j < 4; ++j) {
            int col = bn + tx * 4 + j;
            if (col >= N) continue;
            float v = acc[i][j] + bias[col];
            Y[(size_t)row * N + col] = f2bf(v > 0.f ? v : 0.f);
        }
    }
}

// ---------------------------------------------------------------------------
// amsg[a][:] = sum_j msg[a2b[a][j]][:]   (bf16 in/out, fp32 accumulate)
// one thread per (atom, 4-col chunk): 300/4 = 75 chunks
// ---------------------------------------------------------------------------
__global__ __launch_bounds__(256) void aggregate_k(
    const bf16_t* __restrict__ msg, const int* __restrict__ a2b,
    bf16_t* __restrict__ amsg)
{
    int idx = blockIdx.x * blockDim.x + threadIdx.x;
    const int total = MA_ROWS * 75;
    if (idx >= total) return;
    int a  = idx / 75;
    int c4 = idx - a * 75;
    const int* nb = a2b + (size_t)a * MAX_NB;
    float4 s = make_float4(0.f, 0.f, 0.f, 0.f);
    #pragma unroll
    for (int j = 0; j < MAX_NB; ++j) {
        int b = nb[j];
        ushort4 u = *(const ushort4*)(msg + (size_t)b * HIDDEN + c4 * 4);
        s.x += bf2f(u.x); s.y += bf2f(u.y); s.z += bf2f(u.z); s.w += bf2f(u.w);
    }
    ushort4 o;
    o.x = f2bf(s.x); o.y = f2bf(s.y); o.z = f2bf(s.z); o.w = f2bf(s.w);
    *(ushort4*)(amsg + (size_t)a * HIDDEN + c4 * 4) = o;
}

// ---------------------------------------------------------------------------
// mol_vecs[m][:] = mean over 20 consecutive atom rows (offset by 1), fp32 out
// ---------------------------------------------------------------------------
__global__ __launch_bounds__(256) void mol_mean_k(
    const bf16_t* __restrict__ atom_h, float* __restrict__ out)
{
    int idx = blockIdx.x * blockDim.x + threadIdx.x;
    const int total = N_MOLS * 75;
    if (idx >= total) return;
    int m  = idx / 75;
    int c4 = idx - m * 75;
    const bf16_t* base = atom_h + (size_t)(1 + m * APM) * HIDDEN + c4 * 4;
    float4 s = make_float4(0.f, 0.f, 0.f, 0.f);
    #pragma unroll
    for (int i = 0; i < APM; ++i) {
        ushort4 u = *(const ushort4*)(base + (size_t)i * HIDDEN);
        s.x += bf2f(u.x); s.y += bf2f(u.y); s.z += bf2f(u.z); s.w += bf2f(u.w);
    }
    const float inv = 1.0f / (float)APM;
    s.x *= inv; s.y *= inv; s.z *= inv; s.w *= inv;
    *(float4*)(out + (size_t)m * HIDDEN + c4 * 4) = s;
}

// ---------------------------------------------------------------------------
extern "C" void kernel_launch(void* const* d_in, const int* in_sizes, int n_in,
                              void* d_out, int out_size, void* d_ws, size_t ws_size,
                              hipStream_t stream)
{
    const float* f_atoms = (const float*)d_in[0];
    const float* f_bonds = (const float*)d_in[1];
    const float* W_i     = (const float*)d_in[2];
    const float* W_h     = (const float*)d_in[3];
    const float* W_o     = (const float*)d_in[4];
    const float* b_o     = (const float*)d_in[5];
    const int*   a2b     = (const int*)d_in[6];
    const int*   b2a     = (const int*)d_in[7];
    const int*   b2revb  = (const int*)d_in[8];
    float* out = (float*)d_out;

    // Workspace: bf16 buffers, ~286 MiB total.
    //   inp  [200001 x 300] bf16  (120.0 MB)  — W_i output, persistent addend
    //   msgA [200001 x 300] bf16  (120.0 MB)  — round-1 message / final atom_h
    //   amsg [100001 x 300] bf16  ( 60.0 MB)
    char* base = (char*)d_ws;
    const size_t SZ_BOND_B = (((size_t)MB_ROWS * HIDDEN * sizeof(bf16_t)) + 255) & ~(size_t)255;
    bf16_t* inp  = (bf16_t*)(base);
    bf16_t* msgA = (bf16_t*)(base + SZ_BOND_B);
    bf16_t* amsg = (bf16_t*)(base + 2 * SZ_BOND_B);

    dim3 blk(256);
    dim3 gb((HIDDEN + BN - 1) / BN, (MB_ROWS + BM - 1) / BM);   // 5 x 3126
    dim3 ga((HIDDEN + BN - 1) / BN, (MA_ROWS + BM - 1) / BM);   // 5 x 1563
    int agg_blocks  = (MA_ROWS * 75 + 255) / 256;
    int mean_blocks = (N_MOLS * 75 + 255) / 256;

    // 1) inp = relu(f_bonds @ W_i)
    gemm_in<<<gb, blk, 0, stream>>>(f_bonds, W_i, inp, MB_ROWS);

    // 2) round 0: msgA = relu(inp + (gather from inp) @ W_h)
    aggregate_k<<<agg_blocks, blk, 0, stream>>>(inp, a2b, amsg);
    gemm_mp<<<gb, blk, 0, stream>>>(amsg, inp, b2a, b2revb, W_h, inp, msgA, MB_ROWS);

    // 3) round 1: inp = relu(inp + (gather from msgA) @ W_h)   [in-place safe]
    aggregate_k<<<agg_blocks, blk, 0, stream>>>(msgA, a2b, amsg);
    gemm_mp<<<gb, blk, 0, stream>>>(amsg, msgA, b2a, b2revb, W_h, inp, inp, MB_ROWS);

    // 4) readout: atom_h (aliases msgA) = relu([f_atoms | amsg] @ W_o + b_o)
    aggregate_k<<<agg_blocks, blk, 0, stream>>>(inp, a2b, amsg);
    gemm_out<<<ga, blk, 0, stream>>>(f_atoms, amsg, W_o, b_o, msgA, MA_ROWS);

    // 5) per-molecule mean
    mol_mean_k<<<mean_blocks, blk, 0, stream>>>(msgA, out);
}

// Round 5
// 2237.477 us; speedup vs baseline: 1.1351x; 1.1351x over previous
//
#include <hip/hip_runtime.h>
#include <hip/hip_bf16.h>

// Problem constants (fixed by reference setup_inputs)
#define N_ATOMS   100000
#define N_BONDS   200000
#define MAX_NB    6
#define HIDDEN    300
#define ATOM_FDIM 133
#define BOND_FDIM 147
#define N_MOLS    5000
#define APM       20      // atoms per mol

#define MB_ROWS (N_BONDS + 1)   // 200001
#define MA_ROWS (N_ATOMS + 1)   // 100001

#define BM 64
#define BN 64
#define BK 16

typedef unsigned short bf16_t;
typedef __attribute__((ext_vector_type(8))) __bf16 bf16x8;   // MFMA A/B frag
typedef __attribute__((ext_vector_type(4))) float  float4v;  // MFMA C/D frag

__device__ __forceinline__ float bf2f(unsigned short u) {
    union { unsigned int i; float f; } x; x.i = ((unsigned int)u) << 16; return x.f;
}
__device__ __forceinline__ unsigned short f2bf(float f) {
    union { float f; unsigned int i; } x; x.f = f;
    unsigned int r = x.i + 0x7FFFu + ((x.i >> 16) & 1u);   // RNE (finite values)
    return (unsigned short)(r >> 16);
}

// ===========================================================================
// ROUND-2 PROVEN KERNELS (verbatim): gemm_in, gemm_out, aggregate_k, mol_mean
// ===========================================================================

// GEMM1: Y(bf16) = relu( X(fp32 [M,147]) @ W(fp32 [147,300]) )
__global__ __launch_bounds__(256) void gemm_in(
    const float* __restrict__ X, const float* __restrict__ W,
    bf16_t* __restrict__ Y, int M)
{
    const int K = BOND_FDIM, N = HIDDEN;
    __shared__ float As[BK][BM];
    __shared__ float Bs[BK][BN];
    const int bm = blockIdx.y * BM, bn = blockIdx.x * BN;
    const int tid = threadIdx.x, tx = tid & 15, ty = tid >> 4;
    float acc[4][4] = {};

    for (int k0 = 0; k0 < K; k0 += BK) {
        {   // A tile: 4 scalar loads per thread (147 cols: rows not 16B-aligned)
            int r = tid >> 2, kk = (tid & 3) * 4, row = bm + r;
            #pragma unroll
            for (int t = 0; t < 4; ++t) {
                int k = k0 + kk + t;
                As[kk + t][r] = (row < M && k < K) ? X[(size_t)row * K + k] : 0.f;
            }
        }
        {   // B tile: aligned float4 (W rows are 300 floats = 1200 B)
            int kr_ = tid >> 4, cc = (tid & 15) * 4;
            int krow = k0 + kr_, col = bn + cc;
            float4 v = make_float4(0.f, 0.f, 0.f, 0.f);
            if (krow < K && col < N) v = *(const float4*)(W + (size_t)krow * N + col);
            *(float4*)&Bs[kr_][cc] = v;
        }
        __syncthreads();
        #pragma unroll
        for (int k = 0; k < BK; ++k) {
            float4 a4 = *(float4*)&As[k][ty * 4];
            float4 b4 = *(float4*)&Bs[k][tx * 4];
            float a[4] = {a4.x, a4.y, a4.z, a4.w};
            float b[4] = {b4.x, b4.y, b4.z, b4.w};
            #pragma unroll
            for (int i = 0; i < 4; ++i)
                #pragma unroll
                for (int j = 0; j < 4; ++j)
                    acc[i][j] += a[i] * b[j];
        }
        __syncthreads();
    }
    #pragma unroll
    for (int i = 0; i < 4; ++i) {
        int row = bm + ty * 4 + i;
        if (row >= M) continue;
        #pragma unroll
        for (int j = 0; j < 4; ++j) {
            int col = bn + tx * 4 + j;
            if (col >= N) continue;
            float v = acc[i][j];
            Y[(size_t)row * N + col] = f2bf(v > 0.f ? v : 0.f);
        }
    }
}

// Readout GEMM, virtual concat A = [f_atoms fp32 (133) | amsg bf16 (300)]
__global__ __launch_bounds__(256) void gemm_out(
    const float* __restrict__ f_atoms, const bf16_t* __restrict__ amsg,
    const float* __restrict__ W, const float* __restrict__ bias,
    bf16_t* __restrict__ Y, int M)
{
    const int K = ATOM_FDIM + HIDDEN;   // 433
    const int N = HIDDEN;
    __shared__ float As[BK][BM];
    __shared__ float Bs[BK][BN];
    const int bm = blockIdx.y * BM, bn = blockIdx.x * BN;
    const int tid = threadIdx.x, tx = tid & 15, ty = tid >> 4;
    float acc[4][4] = {};

    for (int k0 = 0; k0 < K; k0 += BK) {
        {
            int r = tid >> 2, kk = (tid & 3) * 4, row = bm + r;
            #pragma unroll
            for (int t = 0; t < 4; ++t) {
                int k = k0 + kk + t;
                float v = 0.f;
                if (row < M && k < K) {
                    v = (k < ATOM_FDIM)
                        ? f_atoms[(size_t)row * ATOM_FDIM + k]
                        : bf2f(amsg[(size_t)row * HIDDEN + (k - ATOM_FDIM)]);
                }
                As[kk + t][r] = v;
            }
        }
        {
            int kr_ = tid >> 4, cc = (tid & 15) * 4;
            int krow = k0 + kr_, col = bn + cc;
            float4 v = make_float4(0.f, 0.f, 0.f, 0.f);
            if (krow < K && col < N) v = *(const float4*)(W + (size_t)krow * N + col);
            *(float4*)&Bs[kr_][cc] = v;
        }
        __syncthreads();
        #pragma unroll
        for (int k = 0; k < BK; ++k) {
            float4 a4 = *(float4*)&As[k][ty * 4];
            float4 b4 = *(float4*)&Bs[k][tx * 4];
            float a[4] = {a4.x, a4.y, a4.z, a4.w};
            float b[4] = {b4.x, b4.y, b4.z, b4.w};
            #pragma unroll
            for (int i = 0; i < 4; ++i)
                #pragma unroll
                for (int j = 0; j < 4; ++j)
                    acc[i][j] += a[i] * b[j];
        }
        __syncthreads();
    }
    #pragma unroll
    for (int i = 0; i < 4; ++i) {
        int row = bm + ty * 4 + i;
        if (row >= M) continue;
        #pragma unroll
        for (int j = 0; j < 4; ++j) {
            int col = bn + tx * 4 + j;
            if (col >= N) continue;
            float v = acc[i][j] + bias[col];
            Y[(size_t)row * N + col] = f2bf(v > 0.f ? v : 0.f);
        }
    }
}

// amsg[a][:] = sum_j msg[a2b[a][j]][:]   (bf16 in/out, fp32 accumulate)
__global__ __launch_bounds__(256) void aggregate_k(
    const bf16_t* __restrict__ msg, const int* __restrict__ a2b,
    bf16_t* __restrict__ amsg)
{
    int idx = blockIdx.x * blockDim.x + threadIdx.x;
    const int total = MA_ROWS * 75;
    if (idx >= total) return;
    int a  = idx / 75;
    int c4 = idx - a * 75;
    const int* nb = a2b + (size_t)a * MAX_NB;
    float4 s = make_float4(0.f, 0.f, 0.f, 0.f);
    #pragma unroll
    for (int j = 0; j < MAX_NB; ++j) {
        int b = nb[j];
        ushort4 u = *(const ushort4*)(msg + (size_t)b * HIDDEN + c4 * 4);
        s.x += bf2f(u.x); s.y += bf2f(u.y); s.z += bf2f(u.z); s.w += bf2f(u.w);
    }
    ushort4 o;
    o.x = f2bf(s.x); o.y = f2bf(s.y); o.z = f2bf(s.z); o.w = f2bf(s.w);
    *(ushort4*)(amsg + (size_t)a * HIDDEN + c4 * 4) = o;
}

// mol_vecs[m][:] = mean over 20 consecutive atom rows (offset by 1), fp32 out
__global__ __launch_bounds__(256) void mol_mean_k(
    const bf16_t* __restrict__ atom_h, float* __restrict__ out)
{
    int idx = blockIdx.x * blockDim.x + threadIdx.x;
    if (idx >= N_MOLS * 75) return;
    int m  = idx / 75;
    int c4 = idx - m * 75;
    const bf16_t* base = atom_h + (size_t)(1 + m * APM) * HIDDEN + c4 * 4;
    float4 s = make_float4(0.f, 0.f, 0.f, 0.f);
    #pragma unroll
    for (int i = 0; i < APM; ++i) {
        ushort4 u = *(const ushort4*)(base + (size_t)i * HIDDEN);
        s.x += bf2f(u.x); s.y += bf2f(u.y); s.z += bf2f(u.z); s.w += bf2f(u.w);
    }
    const float inv = 1.0f / (float)APM;
    s.x *= inv; s.y *= inv; s.z *= inv; s.w *= inv;
    *(float4*)(out + (size_t)m * HIDDEN + c4 * 4) = s;
}

// ===========================================================================
// NEW THIS ROUND — the single bisected change:
// MFMA replacement for round-2's gemm_mp.
//   X[row][k] = amsg[b2a[row]][k] - cur[b2revb[row]][k]   (virtual, bf16)
//   Y(bf16 [M,300]) = relu( addend + X @ W(fp32 [300,300]) )
// Block: 256 thr = 4 waves; tile 128(m) x 64(n); wave = 64m x 32n
// (4 m-tiles x 2 n-tiles of 16x16x32 MFMA). K padded 300->320 (zeros).
// LDS is quad-major: As[q][row][8] holds k = q*8+j, so each fragment is ONE
// contiguous, 16B-aligned bf16x8 (single aligned ds_read_b128; no unions).
// Verified mappings (m89/m74): A m=lane&15, B n=lane&15, k=quad*8+j;
// C/D col=lane&15, row=quad*4+reg. Any consistent A/B k-permutation is
// self-correcting; only the lane->m/n and C/D maps must be exact.
// ===========================================================================
__global__ __launch_bounds__(256) void gemm_mp_mfma(
    const bf16_t* __restrict__ amsg, const bf16_t* __restrict__ cur,
    const int* __restrict__ b2a, const int* __restrict__ b2revb,
    const float* __restrict__ W, const bf16_t* __restrict__ addend,
    bf16_t* __restrict__ Y, int M)
{
    const int S = HIDDEN;   // row stride 300
    __shared__ __align__(16) bf16_t As[4][128][8];   // 8 KB
    __shared__ __align__(16) bf16_t Bs[4][64][8];    // 4 KB

    const int tid  = threadIdx.x;
    const int lane = tid & 63;
    const int w    = tid >> 6;
    const int wm   = w >> 1;          // m-half of block tile (0/1)
    const int wn   = w & 1;           // n-half (0/1)
    const int lrow = lane & 15;
    const int q    = lane >> 4;       // quad 0..3
    const int bm   = blockIdx.y * 128;
    const int n0   = blockIdx.x * 64;

    // A-staging role: thread -> (row 0..127, 16-k half)
    const int sr   = tid >> 1;
    const int sh   = tid & 1;
    const int srow = bm + sr;
    int ra = 0, rrev = 0;
    if (srow < M) { ra = b2a[srow]; rrev = b2revb[srow]; }

    // B-staging role: thread -> (n 0..63, quad 0..3)
    const int stn = tid >> 2;
    const int stq = tid & 3;

    float4v acc[4][2];
    #pragma unroll
    for (int i = 0; i < 4; ++i)
        #pragma unroll
        for (int j = 0; j < 2; ++j) {
            float4v z = {0.f, 0.f, 0.f, 0.f};
            acc[i][j] = z;
        }

    for (int kb = 0; kb < 10; ++kb) {   // K = 320 padded (k>=300 zeros)
        const int k0 = kb * 32;

        // ---- stage B: W fp32 column reads -> bf16, Bs[stq][stn][j]=k0+stq*8+j
        {
            const int col = n0 + stn;
            unsigned short bv[8];
            #pragma unroll
            for (int j = 0; j < 8; ++j) {
                int k = k0 + stq * 8 + j;
                float v = (k < HIDDEN && col < HIDDEN)
                          ? W[(size_t)k * HIDDEN + col] : 0.f;
                bv[j] = f2bf(v);
            }
            *(ushort4*)&Bs[stq][stn][0] = make_ushort4(bv[0], bv[1], bv[2], bv[3]);
            *(ushort4*)&Bs[stq][stn][4] = make_ushort4(bv[4], bv[5], bv[6], bv[7]);
        }

        // ---- stage A: fused gather-subtract, 16 k-elems per thread ------
        {
            const int kbase = k0 + sh * 16;
            unsigned short av[16];
            if (srow < M) {
                const bf16_t* pa = amsg + (size_t)ra   * S;
                const bf16_t* pc = cur  + (size_t)rrev * S;
                #pragma unroll
                for (int c4 = 0; c4 < 4; ++c4) {
                    int k = kbase + c4 * 4;
                    unsigned short* o = &av[c4 * 4];
                    if (k + 4 <= HIDDEN) {   // full in-range ushort4 (8B-aligned)
                        ushort4 u1 = *(const ushort4*)(pa + k);
                        ushort4 u2 = *(const ushort4*)(pc + k);
                        o[0] = f2bf(bf2f(u1.x) - bf2f(u2.x));
                        o[1] = f2bf(bf2f(u1.y) - bf2f(u2.y));
                        o[2] = f2bf(bf2f(u1.z) - bf2f(u2.z));
                        o[3] = f2bf(bf2f(u1.w) - bf2f(u2.w));
                    } else {
                        #pragma unroll
                        for (int j = 0; j < 4; ++j)
                            o[j] = (k + j < HIDDEN)
                                 ? f2bf(bf2f(pa[k + j]) - bf2f(pc[k + j]))
                                 : (unsigned short)0;
                    }
                }
            } else {
                #pragma unroll
                for (int j = 0; j < 16; ++j) av[j] = 0;
            }
            // k-in-block = sh*16 + (0..15) -> quads sh*2 (0..7), sh*2+1 (8..15)
            *(ushort4*)&As[sh * 2][sr][0]     = make_ushort4(av[0],  av[1],  av[2],  av[3]);
            *(ushort4*)&As[sh * 2][sr][4]     = make_ushort4(av[4],  av[5],  av[6],  av[7]);
            *(ushort4*)&As[sh * 2 + 1][sr][0] = make_ushort4(av[8],  av[9],  av[10], av[11]);
            *(ushort4*)&As[sh * 2 + 1][sr][4] = make_ushort4(av[12], av[13], av[14], av[15]);
        }
        __syncthreads();

        // ---- fragments (single aligned 16B loads) + MFMA ----------------
        bf16x8 af[4];
        #pragma unroll
        for (int mt = 0; mt < 4; ++mt)
            af[mt] = *(const bf16x8*)&As[q][wm * 64 + mt * 16 + lrow][0];
        #pragma unroll
        for (int nt = 0; nt < 2; ++nt) {
            bf16x8 bfr = *(const bf16x8*)&Bs[q][wn * 32 + nt * 16 + lrow][0];
            #pragma unroll
            for (int mt = 0; mt < 4; ++mt)
                acc[mt][nt] = __builtin_amdgcn_mfma_f32_16x16x32_bf16(
                    af[mt], bfr, acc[mt][nt], 0, 0, 0);
        }
        __syncthreads();
    }

    // ---- epilogue: C/D col=lane&15, row=quad*4+reg ----------------------
    #pragma unroll
    for (int nt = 0; nt < 2; ++nt) {
        int col = n0 + wn * 32 + nt * 16 + lrow;
        if (col >= HIDDEN) continue;
        #pragma unroll
        for (int mt = 0; mt < 4; ++mt) {
            #pragma unroll
            for (int r = 0; r < 4; ++r) {
                int grow = bm + wm * 64 + mt * 16 + q * 4 + r;
                if (grow >= M) continue;
                float v = acc[mt][nt][r] + bf2f(addend[(size_t)grow * S + col]);
                v = v > 0.f ? v : 0.f;
                Y[(size_t)grow * S + col] = f2bf(v);
            }
        }
    }
}

// ---------------------------------------------------------------------------
extern "C" void kernel_launch(void* const* d_in, const int* in_sizes, int n_in,
                              void* d_out, int out_size, void* d_ws, size_t ws_size,
                              hipStream_t stream)
{
    const float* f_atoms = (const float*)d_in[0];
    const float* f_bonds = (const float*)d_in[1];
    const float* W_i     = (const float*)d_in[2];
    const float* W_h     = (const float*)d_in[3];
    const float* W_o     = (const float*)d_in[4];
    const float* b_o     = (const float*)d_in[5];
    const int*   a2b     = (const int*)d_in[6];
    const int*   b2a     = (const int*)d_in[7];
    const int*   b2revb  = (const int*)d_in[8];
    float* out = (float*)d_out;

    // Workspace: round-2 proven layout (300,002,136 B total)
    char* base = (char*)d_ws;
    const size_t SZ_BOND_B = (((size_t)MB_ROWS * HIDDEN * sizeof(bf16_t)) + 255) & ~(size_t)255;
    bf16_t* inp  = (bf16_t*)(base);
    bf16_t* msgA = (bf16_t*)(base + SZ_BOND_B);
    bf16_t* amsg = (bf16_t*)(base + 2 * SZ_BOND_B);

    dim3 blk(256);
    dim3 gb((HIDDEN + BN - 1) / BN, (MB_ROWS + BM - 1) / BM);   // 5 x 3126
    dim3 ga((HIDDEN + BN - 1) / BN, (MA_ROWS + BM - 1) / BM);   // 5 x 1563
    dim3 gmp(5, (MB_ROWS + 127) / 128);                          // 5 x 1563
    int agg_blocks  = (MA_ROWS * 75 + 255) / 256;
    int mean_blocks = (N_MOLS * 75 + 255) / 256;

    // 1) inp = relu(f_bonds @ W_i)                     [round-2 proven]
    gemm_in<<<gb, blk, 0, stream>>>(f_bonds, W_i, inp, MB_ROWS);

    // 2) round 0: msgA = relu(inp + gather(inp) @ W_h) [MFMA — the change]
    aggregate_k<<<agg_blocks, blk, 0, stream>>>(inp, a2b, amsg);
    gemm_mp_mfma<<<gmp, blk, 0, stream>>>(amsg, inp, b2a, b2revb, W_h, inp, msgA, MB_ROWS);

    // 3) round 1: inp = relu(inp + gather(msgA) @ W_h) [in-place, same-elem]
    aggregate_k<<<agg_blocks, blk, 0, stream>>>(msgA, a2b, amsg);
    gemm_mp_mfma<<<gmp, blk, 0, stream>>>(amsg, msgA, b2a, b2revb, W_h, inp, inp, MB_ROWS);

    // 4) readout: atom_h (=msgA) = relu([f_atoms | amsg] @ W_o + b_o)
    aggregate_k<<<agg_blocks, blk, 0, stream>>>(inp, a2b, amsg);
    gemm_out<<<ga, blk, 0, stream>>>(f_atoms, amsg, W_o, b_o, msgA, MA_ROWS);

    // 5) per-molecule mean
    mol_mean_k<<<mean_blocks, blk, 0, stream>>>(msgA, out);
}

// Round 6
// 1624.040 us; speedup vs baseline: 1.5639x; 1.3777x over previous
//
#include <hip/hip_runtime.h>
#include <hip/hip_bf16.h>

// Problem constants (fixed by reference setup_inputs)
#define N_ATOMS   100000
#define N_BONDS   200000
#define MAX_NB    6
#define HIDDEN    300
#define ATOM_FDIM 133
#define BOND_FDIM 147
#define N_MOLS    5000
#define APM       20      // atoms per mol

#define MB_ROWS (N_BONDS + 1)   // 200001
#define MA_ROWS (N_ATOMS + 1)   // 100001

typedef unsigned short bf16_t;
typedef __attribute__((ext_vector_type(8))) __bf16 bf16x8;   // MFMA A/B frag
typedef __attribute__((ext_vector_type(4))) float  float4v;  // MFMA C/D frag

__device__ __forceinline__ float bf2f(unsigned short u) {
    union { unsigned int i; float f; } x; x.i = ((unsigned int)u) << 16; return x.f;
}
__device__ __forceinline__ unsigned short f2bf(float f) {
    union { float f; unsigned int i; } x; x.f = f;
    unsigned int r = x.i + 0x7FFFu + ((x.i >> 16) & 1u);   // RNE (finite values)
    return (unsigned short)(r >> 16);
}

// ===========================================================================
// Unified MFMA GEMM built on the r5-PROVEN pattern:
//   - quad-major LDS: As[q][row][8], Bs[q][col][8]; every fragment is one
//     contiguous 16B-aligned bf16x8 (single ds_read_b128, no unions)
//   - verified maps: A m=lane&15 k=q*8+j; B n=lane&15 k=q*8+j;
//     C/D col=lane&15 row=q*4+reg
// Block: 512 thr = 8 waves (2m x 4n); tile 128(m) x 320(n) — FULL N in one
// block so per-row gathers happen exactly once. Wave = 64m x 80n
// (4 m-tiles x 5 n-tiles), acc = 20 x float4.
// MODE 0: A = f_bonds fp32 [M,147];            Y = relu(A@W)
// MODE 1: A = amsg[b2a[r]] - cur[b2revb[r]];   Y = relu(addend + A@W)
//         (Y may alias addend: same-element read-before-write only)
// MODE 2: A = [f_atoms fp32 (133) | amsg bf16 (300)]; Y = relu(A@W + bias)
// W is fp32 [K][300] row-major, staged+converted in-kernel (L2-resident).
// ===========================================================================
template<int MODE>
__global__ __launch_bounds__(512) void gemm_mfma(
    const float* __restrict__ Af,
    const bf16_t* __restrict__ Ab1, const bf16_t* __restrict__ Ab2,
    const int* __restrict__ b2a, const int* __restrict__ b2revb,
    const float* __restrict__ W, const float* __restrict__ bias,
    const bf16_t* __restrict__ addend, bf16_t* __restrict__ Y,
    int M, int KB, int K)
{
    const int S = HIDDEN;   // output row stride 300
    __shared__ __align__(16) bf16_t As[4][128][8];   //  8 KB
    __shared__ __align__(16) bf16_t Bs[4][320][8];   // 20 KB

    const int tid  = threadIdx.x;
    const int lane = tid & 63;
    const int w    = tid >> 6;        // 0..7
    const int wm   = w >> 2;          // m-half (0/1): 64 rows
    const int wn   = w & 3;           // n-quarter (0..3): 80 cols
    const int lrow = lane & 15;
    const int q    = lane >> 4;       // quad 0..3
    const int bm   = blockIdx.x * 128;

    // A-staging role: thread -> (row 0..127, quad 0..3), 8 k-elems each
    const int sr   = tid >> 2;
    const int sq   = tid & 3;
    const int srow = bm + sr;
    int ra = 0, rrev = 0;
    if (MODE == 1 && srow < M) { ra = b2a[srow]; rrev = b2revb[srow]; }

    float4v acc[4][5];
    #pragma unroll
    for (int i = 0; i < 4; ++i)
        #pragma unroll
        for (int j = 0; j < 5; ++j) {
            float4v z = {0.f, 0.f, 0.f, 0.f};
            acc[i][j] = z;
        }

    for (int kb = 0; kb < KB; ++kb) {
        const int k0 = kb * 32;

        // ---- stage B: W fp32 -> bf16, Bs[cq][col][j] = W[k0+cq*8+j][col] --
        for (int c = tid; c < 320 * 4; c += 512) {
            const int col = c >> 2;
            const int cq  = c & 3;
            unsigned short bv[8];
            #pragma unroll
            for (int j = 0; j < 8; ++j) {
                int k = k0 + cq * 8 + j;
                float v = (k < K && col < HIDDEN)
                          ? W[(size_t)k * HIDDEN + col] : 0.f;
                bv[j] = f2bf(v);
            }
            *(ushort4*)&Bs[cq][col][0] = make_ushort4(bv[0], bv[1], bv[2], bv[3]);
            *(ushort4*)&Bs[cq][col][4] = make_ushort4(bv[4], bv[5], bv[6], bv[7]);
        }

        // ---- stage A: 8 k-elems per thread -> As[sq][sr][0..7] -----------
        {
            const int kq = k0 + sq * 8;
            unsigned short av[8];
            if (MODE == 0) {
                #pragma unroll
                for (int j = 0; j < 8; ++j) {
                    int k = kq + j;
                    float v = (srow < M && k < BOND_FDIM)
                              ? Af[(size_t)srow * BOND_FDIM + k] : 0.f;
                    av[j] = f2bf(v);
                }
            } else if (MODE == 1) {
                if (srow < M) {
                    const bf16_t* pa = Ab1 + (size_t)ra   * S;
                    const bf16_t* pc = Ab2 + (size_t)rrev * S;
                    #pragma unroll
                    for (int c2 = 0; c2 < 2; ++c2) {
                        int k = kq + c2 * 4;
                        unsigned short* o = &av[c2 * 4];
                        if (k + 4 <= HIDDEN) {   // 8B-aligned ushort4
                            ushort4 u1 = *(const ushort4*)(pa + k);
                            ushort4 u2 = *(const ushort4*)(pc + k);
                            o[0] = f2bf(bf2f(u1.x) - bf2f(u2.x));
                            o[1] = f2bf(bf2f(u1.y) - bf2f(u2.y));
                            o[2] = f2bf(bf2f(u1.z) - bf2f(u2.z));
                            o[3] = f2bf(bf2f(u1.w) - bf2f(u2.w));
                        } else {
                            #pragma unroll
                            for (int j = 0; j < 4; ++j)
                                o[j] = (k + j < HIDDEN)
                                     ? f2bf(bf2f(pa[k + j]) - bf2f(pc[k + j]))
                                     : (unsigned short)0;
                        }
                    }
                } else {
                    #pragma unroll
                    for (int j = 0; j < 8; ++j) av[j] = 0;
                }
            } else {   // MODE 2: [f_atoms(133) | amsg(300)]
                #pragma unroll
                for (int j = 0; j < 8; ++j) {
                    int k = kq + j;
                    float v = 0.f;
                    if (srow < M) {
                        if (k < ATOM_FDIM)
                            v = Af[(size_t)srow * ATOM_FDIM + k];
                        else if (k < ATOM_FDIM + HIDDEN)
                            v = bf2f(Ab1[(size_t)srow * S + (k - ATOM_FDIM)]);
                    }
                    av[j] = f2bf(v);
                }
            }
            *(ushort4*)&As[sq][sr][0] = make_ushort4(av[0], av[1], av[2], av[3]);
            *(ushort4*)&As[sq][sr][4] = make_ushort4(av[4], av[5], av[6], av[7]);
        }
        __syncthreads();

        // ---- fragments (single aligned 16B loads) + MFMA -----------------
        bf16x8 af[4];
        #pragma unroll
        for (int mt = 0; mt < 4; ++mt)
            af[mt] = *(const bf16x8*)&As[q][wm * 64 + mt * 16 + lrow][0];
        #pragma unroll
        for (int nt = 0; nt < 5; ++nt) {
            const int c0 = wn * 80 + nt * 16;
            if (c0 < HIDDEN) {   // skip the all-pad tile (cols 304..319)
                bf16x8 bfr = *(const bf16x8*)&Bs[q][c0 + lrow][0];
                #pragma unroll
                for (int mt = 0; mt < 4; ++mt)
                    acc[mt][nt] = __builtin_amdgcn_mfma_f32_16x16x32_bf16(
                        af[mt], bfr, acc[mt][nt], 0, 0, 0);
            }
        }
        __syncthreads();
    }

    // ---- epilogue: C/D col=lane&15, row=quad*4+reg -----------------------
    #pragma unroll
    for (int nt = 0; nt < 5; ++nt) {
        const int col = wn * 80 + nt * 16 + lrow;
        if (col >= HIDDEN) continue;
        #pragma unroll
        for (int mt = 0; mt < 4; ++mt) {
            #pragma unroll
            for (int r = 0; r < 4; ++r) {
                int grow = bm + wm * 64 + mt * 16 + q * 4 + r;
                if (grow >= M) continue;
                float v = acc[mt][nt][r];
                if (MODE == 1) v += bf2f(addend[(size_t)grow * S + col]);
                if (MODE == 2) v += bias[col];
                v = v > 0.f ? v : 0.f;
                Y[(size_t)grow * S + col] = f2bf(v);
            }
        }
    }
}

// ===========================================================================
// r2/r5-proven: aggregate + mol mean
// ===========================================================================

// amsg[a][:] = sum_j msg[a2b[a][j]][:]   (bf16 in/out, fp32 accumulate)
__global__ __launch_bounds__(256) void aggregate_k(
    const bf16_t* __restrict__ msg, const int* __restrict__ a2b,
    bf16_t* __restrict__ amsg)
{
    int idx = blockIdx.x * blockDim.x + threadIdx.x;
    const int total = MA_ROWS * 75;
    if (idx >= total) return;
    int a  = idx / 75;
    int c4 = idx - a * 75;
    const int* nb = a2b + (size_t)a * MAX_NB;
    float4 s = make_float4(0.f, 0.f, 0.f, 0.f);
    #pragma unroll
    for (int j = 0; j < MAX_NB; ++j) {
        int b = nb[j];
        ushort4 u = *(const ushort4*)(msg + (size_t)b * HIDDEN + c4 * 4);
        s.x += bf2f(u.x); s.y += bf2f(u.y); s.z += bf2f(u.z); s.w += bf2f(u.w);
    }
    ushort4 o;
    o.x = f2bf(s.x); o.y = f2bf(s.y); o.z = f2bf(s.z); o.w = f2bf(s.w);
    *(ushort4*)(amsg + (size_t)a * HIDDEN + c4 * 4) = o;
}

// mol_vecs[m][:] = mean over 20 consecutive atom rows (offset by 1), fp32 out
__global__ __launch_bounds__(256) void mol_mean_k(
    const bf16_t* __restrict__ atom_h, float* __restrict__ out)
{
    int idx = blockIdx.x * blockDim.x + threadIdx.x;
    if (idx >= N_MOLS * 75) return;
    int m  = idx / 75;
    int c4 = idx - m * 75;
    const bf16_t* base = atom_h + (size_t)(1 + m * APM) * HIDDEN + c4 * 4;
    float4 s = make_float4(0.f, 0.f, 0.f, 0.f);
    #pragma unroll
    for (int i = 0; i < APM; ++i) {
        ushort4 u = *(const ushort4*)(base + (size_t)i * HIDDEN);
        s.x += bf2f(u.x); s.y += bf2f(u.y); s.z += bf2f(u.z); s.w += bf2f(u.w);
    }
    const float inv = 1.0f / (float)APM;
    s.x *= inv; s.y *= inv; s.z *= inv; s.w *= inv;
    *(float4*)(out + (size_t)m * HIDDEN + c4 * 4) = s;
}

// ---------------------------------------------------------------------------
extern "C" void kernel_launch(void* const* d_in, const int* in_sizes, int n_in,
                              void* d_out, int out_size, void* d_ws, size_t ws_size,
                              hipStream_t stream)
{
    const float* f_atoms = (const float*)d_in[0];
    const float* f_bonds = (const float*)d_in[1];
    const float* W_i     = (const float*)d_in[2];
    const float* W_h     = (const float*)d_in[3];
    const float* W_o     = (const float*)d_in[4];
    const float* b_o     = (const float*)d_in[5];
    const int*   a2b     = (const int*)d_in[6];
    const int*   b2a     = (const int*)d_in[7];
    const int*   b2revb  = (const int*)d_in[8];
    float* out = (float*)d_out;

    // Workspace: r2/r5-proven layout (300,002,136 B total)
    char* base = (char*)d_ws;
    const size_t SZ_BOND_B = (((size_t)MB_ROWS * HIDDEN * sizeof(bf16_t)) + 255) & ~(size_t)255;
    bf16_t* inp  = (bf16_t*)(base);
    bf16_t* msgA = (bf16_t*)(base + SZ_BOND_B);
    bf16_t* amsg = (bf16_t*)(base + 2 * SZ_BOND_B);

    dim3 blk512(512), blk256(256);
    const int gb = (MB_ROWS + 127) / 128;   // 1563
    const int ga = (MA_ROWS + 127) / 128;   // 782
    int agg_blocks  = (MA_ROWS * 75 + 255) / 256;
    int mean_blocks = (N_MOLS * 75 + 255) / 256;

    // 1) inp = relu(f_bonds @ W_i)
    gemm_mfma<0><<<gb, blk512, 0, stream>>>(
        f_bonds, nullptr, nullptr, nullptr, nullptr,
        W_i, nullptr, nullptr, inp, MB_ROWS, 5, BOND_FDIM);

    // 2) round 0: msgA = relu(inp + (agg -> gather-sub) @ W_h)
    aggregate_k<<<agg_blocks, blk256, 0, stream>>>(inp, a2b, amsg);
    gemm_mfma<1><<<gb, blk512, 0, stream>>>(
        nullptr, amsg, inp, b2a, b2revb,
        W_h, nullptr, inp, msgA, MB_ROWS, 10, HIDDEN);

    // 3) round 1: inp = relu(inp + ...) in-place (same-element alias only)
    aggregate_k<<<agg_blocks, blk256, 0, stream>>>(msgA, a2b, amsg);
    gemm_mfma<1><<<gb, blk512, 0, stream>>>(
        nullptr, amsg, msgA, b2a, b2revb,
        W_h, nullptr, inp, inp, MB_ROWS, 10, HIDDEN);

    // 4) readout: atom_h (=msgA) = relu([f_atoms | agg(inp)] @ W_o + b_o)
    aggregate_k<<<agg_blocks, blk256, 0, stream>>>(inp, a2b, amsg);
    gemm_mfma<2><<<ga, blk512, 0, stream>>>(
        f_atoms, amsg, nullptr, nullptr, nullptr,
        W_o, b_o, nullptr, msgA, MA_ROWS, 14, ATOM_FDIM + HIDDEN);

    // 5) per-molecule mean
    mol_mean_k<<<mean_blocks, blk256, 0, stream>>>(msgA, out);
}

// Round 7
// 1207.378 us; speedup vs baseline: 2.1036x; 1.3451x over previous
//
#include <hip/hip_runtime.h>
#include <hip/hip_bf16.h>

// Problem constants (fixed by reference setup_inputs)
#define N_ATOMS   100000
#define N_BONDS   200000
#define MAX_NB    6
#define HIDDEN    300
#define ATOM_FDIM 133
#define BOND_FDIM 147
#define N_MOLS    5000
#define APM       20      // atoms per mol

#define MB_ROWS (N_BONDS + 1)   // 200001
#define MA_ROWS (N_ATOMS + 1)   // 100001

#define CHUNKS_B 1280     // 16B chunks per k-block image: 4*320*8 bf16 = 20480 B

typedef unsigned short bf16_t;
typedef __attribute__((ext_vector_type(8))) __bf16 bf16x8;   // MFMA A/B frag
typedef __attribute__((ext_vector_type(4))) float  float4v;  // MFMA C/D frag

__device__ __forceinline__ float bf2f(unsigned short u) {
    union { unsigned int i; float f; } x; x.i = ((unsigned int)u) << 16; return x.f;
}
__device__ __forceinline__ unsigned short f2bf(float f) {
    union { float f; unsigned int i; } x; x.f = f;
    unsigned int r = x.i + 0x7FFFu + ((x.i >> 16) & 1u);   // RNE (finite values)
    return (unsigned short)(r >> 16);
}

// async 16B global->LDS (m97-verified builtin); fallback to manual copy
__device__ __forceinline__ void g2lds16(const bf16_t* g, bf16_t* l) {
#if __has_builtin(__builtin_amdgcn_global_load_lds)
    __builtin_amdgcn_global_load_lds(
        (const __attribute__((address_space(1))) unsigned int*)g,
        (__attribute__((address_space(3))) unsigned int*)l, 16, 0, 0);
#else
    *(uint4*)l = *(const uint4*)g;
#endif
}

// ===========================================================================
// Weight prep: W fp32 [K][300] row-major -> bf16 k-block images matching the
// Bs LDS layout exactly: chunk c (16 B) of block kb holds, for cq=c/320,
// col=c%320: W[kb*32+cq*8+j][col], j=0..7; zero-padded (k>=K or col>=300).
// ===========================================================================
__global__ __launch_bounds__(256) void prep_w(
    const float* __restrict__ W, bf16_t* __restrict__ dst, int K, int total_chunks)
{
    int idx = blockIdx.x * 256 + threadIdx.x;
    if (idx >= total_chunks) return;
    int kb  = idx / CHUNKS_B;
    int c   = idx - kb * CHUNKS_B;
    int cq  = c / 320;
    int col = c - cq * 320;
    unsigned short v[8];
    #pragma unroll
    for (int j = 0; j < 8; ++j) {
        int k = kb * 32 + cq * 8 + j;
        float f = (k < K && col < HIDDEN) ? W[(size_t)k * HIDDEN + col] : 0.f;
        v[j] = f2bf(f);
    }
    bf16_t* p = dst + (size_t)idx * 8;
    *(ushort4*)(p)     = make_ushort4(v[0], v[1], v[2], v[3]);
    *(ushort4*)(p + 4) = make_ushort4(v[4], v[5], v[6], v[7]);
}

// ===========================================================================
// Unified MFMA GEMM (r5/r6-proven core):
//   - quad-major LDS: As[q][row][8], Bs[q][col][8]; every fragment one
//     contiguous 16B-aligned bf16x8 (single ds_read_b128)
//   - verified maps: A m=lane&15 k=q*8+j; B n=lane&15 k=q*8+j;
//     C/D col=lane&15 row=q*4+reg
// Block: 512 thr = 8 waves (2m x 4n); tile 128(m) x 320(n) — full N per
// block, per-row gathers exactly once. Wave = 64m x 80n.
// NEW (r7): B staged from PRE-BLOCKED bf16 weights via async
// global_load_lds (16B/lane), issued before A staging so DMA overlaps it.
// MODE 0: A = f_bonds fp32 [M,147];            Y = relu(A@W)
// MODE 1: A = amsg[b2a[r]] - cur[b2revb[r]];   Y = relu(addend + A@W)
//         (Y may alias addend: same-element read-before-write only)
// MODE 2: A = [f_atoms fp32 (133) | amsg bf16 (300)]; Y = relu(A@W + bias)
// ===========================================================================
template<int MODE>
__global__ __launch_bounds__(512) void gemm_mfma(
    const float* __restrict__ Af,
    const bf16_t* __restrict__ Ab1, const bf16_t* __restrict__ Ab2,
    const int* __restrict__ b2a, const int* __restrict__ b2revb,
    const bf16_t* __restrict__ WB, const float* __restrict__ bias,
    const bf16_t* __restrict__ addend, bf16_t* __restrict__ Y,
    int M, int KB)
{
    const int S = HIDDEN;   // output row stride 300
    __shared__ __align__(16) bf16_t As[4][128][8];   //  8 KB
    __shared__ __align__(16) bf16_t Bs[4][320][8];   // 20 KB

    const int tid  = threadIdx.x;
    const int lane = tid & 63;
    const int w    = tid >> 6;        // 0..7
    const int wm   = w >> 2;          // m-half (0/1): 64 rows
    const int wn   = w & 3;           // n-quarter (0..3): 80 cols
    const int lrow = lane & 15;
    const int q    = lane >> 4;       // quad 0..3
    const int bm   = blockIdx.x * 128;

    // A-staging role: thread -> (row 0..127, quad 0..3), 8 k-elems each
    const int sr   = tid >> 2;
    const int sq   = tid & 3;
    const int srow = bm + sr;
    int ra = 0, rrev = 0;
    if (MODE == 1 && srow < M) { ra = b2a[srow]; rrev = b2revb[srow]; }

    bf16_t* BsL = &Bs[0][0][0];

    float4v acc[4][5];
    #pragma unroll
    for (int i = 0; i < 4; ++i)
        #pragma unroll
        for (int j = 0; j < 5; ++j) {
            float4v z = {0.f, 0.f, 0.f, 0.f};
            acc[i][j] = z;
        }

    for (int kb = 0; kb < KB; ++kb) {
        // ---- issue async B copy: 20480 B linear, 16 B/lane --------------
        // wave handles 64-chunk groups cc = w, w+8, w+16 (<20)
        {
            const bf16_t* wsrc = WB + (size_t)kb * (CHUNKS_B * 8);
            #pragma unroll
            for (int c0 = 0; c0 < 3; ++c0) {
                int cc = w + c0 * 8;
                if (cc < 20)
                    g2lds16(wsrc + cc * 512 + lane * 8, BsL + cc * 512 + lane * 8);
            }
        }

        // ---- stage A: 8 k-elems per thread -> As[sq][sr][0..7] -----------
        {
            const int kq = kb * 32 + sq * 8;
            unsigned short av[8];
            if (MODE == 0) {
                #pragma unroll
                for (int j = 0; j < 8; ++j) {
                    int k = kq + j;
                    float v = (srow < M && k < BOND_FDIM)
                              ? Af[(size_t)srow * BOND_FDIM + k] : 0.f;
                    av[j] = f2bf(v);
                }
            } else if (MODE == 1) {
                if (srow < M) {
                    const bf16_t* pa = Ab1 + (size_t)ra   * S;
                    const bf16_t* pc = Ab2 + (size_t)rrev * S;
                    #pragma unroll
                    for (int c2 = 0; c2 < 2; ++c2) {
                        int k = kq + c2 * 4;
                        unsigned short* o = &av[c2 * 4];
                        if (k + 4 <= HIDDEN) {   // 8B-aligned ushort4
                            ushort4 u1 = *(const ushort4*)(pa + k);
                            ushort4 u2 = *(const ushort4*)(pc + k);
                            o[0] = f2bf(bf2f(u1.x) - bf2f(u2.x));
                            o[1] = f2bf(bf2f(u1.y) - bf2f(u2.y));
                            o[2] = f2bf(bf2f(u1.z) - bf2f(u2.z));
                            o[3] = f2bf(bf2f(u1.w) - bf2f(u2.w));
                        } else {
                            #pragma unroll
                            for (int j = 0; j < 4; ++j)
                                o[j] = (k + j < HIDDEN)
                                     ? f2bf(bf2f(pa[k + j]) - bf2f(pc[k + j]))
                                     : (unsigned short)0;
                        }
                    }
                } else {
                    #pragma unroll
                    for (int j = 0; j < 8; ++j) av[j] = 0;
                }
            } else {   // MODE 2: [f_atoms(133) | amsg(300)]
                #pragma unroll
                for (int j = 0; j < 8; ++j) {
                    int k = kq + j;
                    float v = 0.f;
                    if (srow < M) {
                        if (k < ATOM_FDIM)
                            v = Af[(size_t)srow * ATOM_FDIM + k];
                        else if (k < ATOM_FDIM + HIDDEN)
                            v = bf2f(Ab1[(size_t)srow * S + (k - ATOM_FDIM)]);
                    }
                    av[j] = f2bf(v);
                }
            }
            *(ushort4*)&As[sq][sr][0] = make_ushort4(av[0], av[1], av[2], av[3]);
            *(ushort4*)&As[sq][sr][4] = make_ushort4(av[4], av[5], av[6], av[7]);
        }
        __syncthreads();   // drains vmcnt (B DMA) + lgkm (A writes) + barrier

        // ---- fragments (single aligned 16B loads) + MFMA -----------------
        bf16x8 af[4];
        #pragma unroll
        for (int mt = 0; mt < 4; ++mt)
            af[mt] = *(const bf16x8*)&As[q][wm * 64 + mt * 16 + lrow][0];
        #pragma unroll
        for (int nt = 0; nt < 5; ++nt) {
            const int c0 = wn * 80 + nt * 16;
            if (c0 < HIDDEN) {   // skip the all-pad tile (cols 304..319)
                bf16x8 bfr = *(const bf16x8*)&Bs[q][c0 + lrow][0];
                #pragma unroll
                for (int mt = 0; mt < 4; ++mt)
                    acc[mt][nt] = __builtin_amdgcn_mfma_f32_16x16x32_bf16(
                        af[mt], bfr, acc[mt][nt], 0, 0, 0);
            }
        }
        __syncthreads();   // all waves done reading LDS before next stores
    }

    // ---- epilogue: C/D col=lane&15, row=quad*4+reg -----------------------
    #pragma unroll
    for (int nt = 0; nt < 5; ++nt) {
        const int col = wn * 80 + nt * 16 + lrow;
        if (col >= HIDDEN) continue;
        #pragma unroll
        for (int mt = 0; mt < 4; ++mt) {
            #pragma unroll
            for (int r = 0; r < 4; ++r) {
                int grow = bm + wm * 64 + mt * 16 + q * 4 + r;
                if (grow >= M) continue;
                float v = acc[mt][nt][r];
                if (MODE == 1) v += bf2f(addend[(size_t)grow * S + col]);
                if (MODE == 2) v += bias[col];
                v = v > 0.f ? v : 0.f;
                Y[(size_t)grow * S + col] = f2bf(v);
            }
        }
    }
}

// ===========================================================================
// r2/r5-proven: aggregate + mol mean
// ===========================================================================

// amsg[a][:] = sum_j msg[a2b[a][j]][:]   (bf16 in/out, fp32 accumulate)
__global__ __launch_bounds__(256) void aggregate_k(
    const bf16_t* __restrict__ msg, const int* __restrict__ a2b,
    bf16_t* __restrict__ amsg)
{
    int idx = blockIdx.x * blockDim.x + threadIdx.x;
    const int total = MA_ROWS * 75;
    if (idx >= total) return;
    int a  = idx / 75;
    int c4 = idx - a * 75;
    const int* nb = a2b + (size_t)a * MAX_NB;
    float4 s = make_float4(0.f, 0.f, 0.f, 0.f);
    #pragma unroll
    for (int j = 0; j < MAX_NB; ++j) {
        int b = nb[j];
        ushort4 u = *(const ushort4*)(msg + (size_t)b * HIDDEN + c4 * 4);
        s.x += bf2f(u.x); s.y += bf2f(u.y); s.z += bf2f(u.z); s.w += bf2f(u.w);
    }
    ushort4 o;
    o.x = f2bf(s.x); o.y = f2bf(s.y); o.z = f2bf(s.z); o.w = f2bf(s.w);
    *(ushort4*)(amsg + (size_t)a * HIDDEN + c4 * 4) = o;
}

// mol_vecs[m][:] = mean over 20 consecutive atom rows (offset by 1), fp32 out
__global__ __launch_bounds__(256) void mol_mean_k(
    const bf16_t* __restrict__ atom_h, float* __restrict__ out)
{
    int idx = blockIdx.x * blockDim.x + threadIdx.x;
    if (idx >= N_MOLS * 75) return;
    int m  = idx / 75;
    int c4 = idx - m * 75;
    const bf16_t* base = atom_h + (size_t)(1 + m * APM) * HIDDEN + c4 * 4;
    float4 s = make_float4(0.f, 0.f, 0.f, 0.f);
    #pragma unroll
    for (int i = 0; i < APM; ++i) {
        ushort4 u = *(const ushort4*)(base + (size_t)i * HIDDEN);
        s.x += bf2f(u.x); s.y += bf2f(u.y); s.z += bf2f(u.z); s.w += bf2f(u.w);
    }
    const float inv = 1.0f / (float)APM;
    s.x *= inv; s.y *= inv; s.z *= inv; s.w *= inv;
    *(float4*)(out + (size_t)m * HIDDEN + c4 * 4) = s;
}

// ---------------------------------------------------------------------------
extern "C" void kernel_launch(void* const* d_in, const int* in_sizes, int n_in,
                              void* d_out, int out_size, void* d_ws, size_t ws_size,
                              hipStream_t stream)
{
    const float* f_atoms = (const float*)d_in[0];
    const float* f_bonds = (const float*)d_in[1];
    const float* W_i     = (const float*)d_in[2];
    const float* W_h     = (const float*)d_in[3];
    const float* W_o     = (const float*)d_in[4];
    const float* b_o     = (const float*)d_in[5];
    const int*   a2b     = (const int*)d_in[6];
    const int*   b2a     = (const int*)d_in[7];
    const int*   b2revb  = (const int*)d_in[8];
    float* out = (float*)d_out;

    // Workspace: r2/r5/r6-proven layout (300,002,136 B — do NOT grow d_ws!)
    char* base = (char*)d_ws;
    const size_t SZ_BOND_B = (((size_t)MB_ROWS * HIDDEN * sizeof(bf16_t)) + 255) & ~(size_t)255;
    bf16_t* inp  = (bf16_t*)(base);
    bf16_t* msgA = (bf16_t*)(base + SZ_BOND_B);
    bf16_t* amsg = (bf16_t*)(base + 2 * SZ_BOND_B);

    // Pre-blocked bf16 weights live in d_out scratch (6 MB; 593,920 B used).
    // Safe: fully consumed before mol_mean_k overwrites every output element.
    char* scratch = (char*)d_out;
    bf16_t* Wib = (bf16_t*)(scratch);                 //  5 kb * 20480 B = 102,400
    bf16_t* Whb = (bf16_t*)(scratch + 102400);        // 10 kb           = 204,800
    bf16_t* Wob = (bf16_t*)(scratch + 307200);        // 14 kb           = 286,720

    dim3 blk512(512), blk256(256);
    const int gb = (MB_ROWS + 127) / 128;   // 1563
    const int ga = (MA_ROWS + 127) / 128;   // 782
    int agg_blocks  = (MA_ROWS * 75 + 255) / 256;
    int mean_blocks = (N_MOLS * 75 + 255) / 256;

    // 0) weight prep (tiny)
    prep_w<<<(5  * CHUNKS_B + 255) / 256, blk256, 0, stream>>>(W_i, Wib, BOND_FDIM, 5 * CHUNKS_B);
    prep_w<<<(10 * CHUNKS_B + 255) / 256, blk256, 0, stream>>>(W_h, Whb, HIDDEN, 10 * CHUNKS_B);
    prep_w<<<(14 * CHUNKS_B + 255) / 256, blk256, 0, stream>>>(W_o, Wob, ATOM_FDIM + HIDDEN, 14 * CHUNKS_B);

    // 1) inp = relu(f_bonds @ W_i)
    gemm_mfma<0><<<gb, blk512, 0, stream>>>(
        f_bonds, nullptr, nullptr, nullptr, nullptr,
        Wib, nullptr, nullptr, inp, MB_ROWS, 5);

    // 2) round 0: msgA = relu(inp + (agg -> gather-sub) @ W_h)
    aggregate_k<<<agg_blocks, blk256, 0, stream>>>(inp, a2b, amsg);
    gemm_mfma<1><<<gb, blk512, 0, stream>>>(
        nullptr, amsg, inp, b2a, b2revb,
        Whb, nullptr, inp, msgA, MB_ROWS, 10);

    // 3) round 1: inp = relu(inp + ...) in-place (same-element alias only)
    aggregate_k<<<agg_blocks, blk256, 0, stream>>>(msgA, a2b, amsg);
    gemm_mfma<1><<<gb, blk512, 0, stream>>>(
        nullptr, amsg, msgA, b2a, b2revb,
        Whb, nullptr, inp, inp, MB_ROWS, 10);

    // 4) readout: atom_h (=msgA) = relu([f_atoms | agg(inp)] @ W_o + b_o)
    aggregate_k<<<agg_blocks, blk256, 0, stream>>>(inp, a2b, amsg);
    gemm_mfma<2><<<ga, blk512, 0, stream>>>(
        f_atoms, amsg, nullptr, nullptr, nullptr,
        Wob, b_o, nullptr, msgA, MA_ROWS, 14);

    // 5) per-molecule mean
    mol_mean_k<<<mean_blocks, blk256, 0, stream>>>(msgA, out);
}